// Round 18
// baseline (59.949 us; speedup 1.0000x reference)
//
#include <hip/hip_runtime.h>
#include <hip/hip_bf16.h>

// Problem constants
#define L_SEQ   4096
#define D_IN    1024
#define N_BATCH 16
#define L_OUT   1024
#define D_OUT   1024
#define M_DIM   (N_BATCH * L_OUT)   // 16384
#define K_DIM   D_IN

// GEMM tiling: 128x128, BK=32, fp32-A direct-from-x, 2 blocks/CU
#define BM 128
#define BN 128
#define BK 32
#define NKT (K_DIM / BK)   // 32

typedef __attribute__((ext_vector_type(4))) float  f32x4;
typedef __attribute__((ext_vector_type(8))) __bf16 bf16x8;
typedef __attribute__((ext_vector_type(4))) __bf16 bf16x4;

// ws layout (bytes): W bf16 (2 MiB) + s_arr
#define WS_W_OFF 0u
#define WS_S_OFF (4u * 1024u * 1024u)

// ---------------------------------------------------------------------------
// Kernel 1 (prep): blocks 0..15 -> mask sums; blocks 16..1039 -> W rows.
// W swizzle (32-elem groups): 8-elem slot sl -> sl ^ ((row>>1)&3).
// ---------------------------------------------------------------------------
__global__ __launch_bounds__(256) void prep_kernel(
    const int*   __restrict__ mask,  // (16, 4096)
    const float* __restrict__ W,     // (1024, 1024)
    int*    __restrict__ s_out,      // (16,)
    __bf16* __restrict__ wsW)        // (1024, 1024) swizzled
{
    const int t = threadIdx.x;
    if (blockIdx.x < 16) {
        const int b = blockIdx.x;
        const int* row = mask + (size_t)b * L_SEQ;
        int sum = 0;
#pragma unroll
        for (int i = 0; i < L_SEQ / 256; ++i) sum += row[t + i * 256];
#pragma unroll
        for (int off = 32; off > 0; off >>= 1) sum += __shfl_down(sum, off, 64);
        __shared__ int wsum[4];
        if ((t & 63) == 0) wsum[t >> 6] = sum;
        __syncthreads();
        if (t == 0) {
            int total = wsum[0] + wsum[1] + wsum[2] + wsum[3];
            s_out[b] = total < L_OUT ? total : L_OUT;
        }
    } else {
        const int n  = blockIdx.x - 16;          // 0..1023
        const int e0 = t * 4;
        const int sl   = (e0 >> 3) & 3;
        const int dste = (e0 & ~31) | ((sl ^ ((n >> 1) & 3)) << 3) | (e0 & 7);
        const float* src = W + (size_t)n * D_IN + e0;
        f32x4 v = *(const f32x4*)src;
        bf16x4 o = {(__bf16)v.x, (__bf16)v.y, (__bf16)v.z, (__bf16)v.w};
        *(bf16x4*)(wsW + (size_t)n * K_DIM + dste) = o;
    }
}

// ---------------------------------------------------------------------------
// Kernel 2: fused GEMM, A staged fp32 DIRECTLY from x via global_load_lds.
// CHANGE vs R17: 128x128 tile, 256 thr (4 waves 2Mx2N), 64 KiB LDS ->
// 2 blocks/CU. Two independent barrier domains per CU cover each other's
// drain stalls (m103: 128^2=912 > 256^2=792 TF at this structure class;
// m114 co-scheduling). Single phase per kt (16 MFMA, 1 barrier) -> 32
// barriers total (was 64).
// vmcnt ledger: prologue A(0)4,B(0)2,A(1)4; per-kt issue [B(kt+1)2][A(kt+2)4];
//   at P(kt): outstanding [A(kt)4? retired][...] -> steady vmcnt(4) retires
//   A(kt)+B(kt), leaves A(kt+1)4. Last kt: vmcnt(0).
// WRITE-SAFETY (R15 lesson): A(kt+2)->a2, last read P(kt-1), separated by
// P(kt) barrier; B(kt+1)->nxt, last read P(kt-1), same separation. Stages
// are issued AFTER the barrier; readers were before it. No same-phase
// overwrite of any read set.
// ---------------------------------------------------------------------------
__device__ __forceinline__ void gload16v(const void* g, void* l) {
    __builtin_amdgcn_global_load_lds(
        (const __attribute__((address_space(1))) void*)g,
        (__attribute__((address_space(3))) void*)l,
        16, 0, 0);
}

#define FENCE() asm volatile("" ::: "memory")

__global__ __launch_bounds__(256, 2) void gemm_kernel(
    const float*  __restrict__ x,    // (16, 4096, 1024) fp32
    const __bf16* __restrict__ Wb,   // (1024, 1024) swizzled bf16
    const float*  __restrict__ bias, // (1024,)
    const int*    __restrict__ s_arr,// (16,)
    float* __restrict__ out)         // (16384, 1024)
{
    __shared__ float  sAf[3][BM * BK];   // 48 KiB (fp32 A, triple buffer)
    __shared__ __bf16 sB [2][BN * BK];   // 16 KiB (bf16 B, double buffer)

    const int t  = threadIdx.x;       // 0..255
    const int bx = blockIdx.x;        // 1024 blocks
    const int vb = (bx & 7) * 128 + (bx >> 3);  // T1: tile_m sharers on 1 XCD
    const int tile_n = vb & 7;        // N/BN = 8
    const int tile_m = vb >> 3;       // M/BM = 128
    const int m0 = tile_m * BM;
    const int n0 = tile_n * BN;
    const int lane = t & 63;
    const int wave = t >> 6;          // 0..3
    const int wm = wave & 1;          // 2M
    const int wn = wave >> 1;         // 2N

    // ---- A staging geometry (4 rounds x 32 rows x 32 f32) ----
    const int bb = m0 >> 10;
    const int s  = s_arr[bb];
    const int jb = m0 & (L_OUT - 1);
    const float* xb = x + (size_t)bb * L_SEQ * D_IN;
    const int ascol = (((t & 7) ^ ((t >> 3) & 7)) * 4);   // swizzled SOURCE col
    const float* asrc[4];
    int  adst[4];
    int  arow[4];
#pragma unroll
    for (int r = 0; r < 4; ++r) {
        const int rr = 32 * r + (t >> 3);        // row in tile 0..127
        const int j  = jb + rr;
        const int xr = (j < s) ? (L_SEQ - s + j) : 0;  // clamped-safe
        asrc[r] = xb + (size_t)xr * D_IN + ascol;
        adst[r] = rr * BK + (t & 7) * 4;         // linear dest (f32 elems)
        arow[r] = j;
    }
#define STAGE_A(abuf, kt_)                                                 \
    {                                                                      \
        _Pragma("unroll")                                                  \
        for (int r = 0; r < 4; ++r)                                        \
            gload16v(asrc[r] + (kt_) * BK, (abuf) + adst[r]);              \
    }

    // ---- B staging geometry (2 rounds x 64 rows x 32 bf16) ----
    const __bf16* Bg = Wb + (size_t)n0 * K_DIM;
    const int brow = t >> 2;          // 0..63
    const int bcol = (t & 3) * 8;     // elem col (linear; content swizzled)
#define STAGE_B(buf, kt_)                                                  \
    {                                                                      \
        _Pragma("unroll")                                                  \
        for (int r = 0; r < 2; ++r) {                                      \
            const int row_ = 64 * r + brow;                                \
            gload16v(Bg + (size_t)row_ * K_DIM + (kt_) * BK + bcol,        \
                     &sB[buf][row_ * BK + bcol]);                          \
        }                                                                  \
    }

    // ---- fragment read geometry ----
    const int fr = lane & 15;
    const int g4 = lane >> 4;         // 0..3 (k-group)

    float bias_v[4];
#pragma unroll
    for (int q = 0; q < 4; ++q)
        bias_v[q] = bias[n0 + wn * 64 + q * 16 + fr];

    bf16x8 aF[4], bB[4];
    f32x4 acc[4][4];
#pragma unroll
    for (int i = 0; i < 4; ++i)
#pragma unroll
        for (int q = 0; q < 4; ++q) acc[i][q] = (f32x4){0.f, 0.f, 0.f, 0.f};

    // A frag: R = wm*64 + i*16 + fr; slots (2g4, 2g4+1) ^ (R&7)
#define LOAD_A32(abuf)                                                     \
    {                                                                      \
        _Pragma("unroll")                                                  \
        for (int i = 0; i < 4; ++i) {                                      \
            const int R_ = wm * 64 + i * 16 + fr;                          \
            const float* rbase_ = (abuf) + R_ * BK;                        \
            f32x4 lo_ = *(const f32x4*)&rbase_[((2*g4)   ^ (R_ & 7)) * 4]; \
            f32x4 hi_ = *(const f32x4*)&rbase_[((2*g4+1) ^ (R_ & 7)) * 4]; \
            aF[i] = (bf16x8){(__bf16)lo_.x, (__bf16)lo_.y, (__bf16)lo_.z,  \
                             (__bf16)lo_.w, (__bf16)hi_.x, (__bf16)hi_.y,  \
                             (__bf16)hi_.z, (__bf16)hi_.w};                \
        }                                                                  \
    }

    // B frag: RB = wn*64 + j*16 + fr; slot g4 ^ ((RB>>1)&3)
#define LOAD_B4(buf)                                                       \
    {                                                                      \
        _Pragma("unroll")                                                  \
        for (int j = 0; j < 4; ++j) {                                      \
            const int RB_ = wn * 64 + j * 16 + fr;                         \
            bB[j] = *(const bf16x8*)                                       \
                &sB[buf][RB_ * BK + (g4 ^ ((RB_ >> 1) & 3)) * 8];          \
        }                                                                  \
    }

#define MFMA16()                                                           \
    {                                                                      \
        _Pragma("unroll")                                                  \
        for (int i = 0; i < 4; ++i)                                        \
            _Pragma("unroll")                                              \
            for (int j = 0; j < 4; ++j)                                    \
                acc[i][j] = __builtin_amdgcn_mfma_f32_16x16x32_bf16(       \
                    aF[i], bB[j], acc[i][j], 0, 0, 0);                     \
    }

    // rotating A buffers: a0 = A(kt), a1 = A(kt+1), a2 = stage target A(kt+2)
    float* a0 = &sAf[0][0];
    float* a1 = &sAf[1][0];
    float* a2 = &sAf[2][0];

    // ---- prologue: A(0)[4], B(0)[2], A(1)[4] ----
    STAGE_A(a0, 0);
    STAGE_B(0, 0);
    STAGE_A(a1, 1);

    for (int kt = 0; kt < NKT; ++kt) {
        const int cur = kt & 1;
        const int nxt = cur ^ 1;

        FENCE();
        if (kt == NKT - 1) asm volatile("s_waitcnt vmcnt(0)" ::: "memory");
        else               asm volatile("s_waitcnt vmcnt(4)" ::: "memory");
        __builtin_amdgcn_s_barrier();
        FENCE();
        if (s < L_OUT) {        // cold path: zero masked rows (block-uniform)
#pragma unroll
            for (int r = 0; r < 4; ++r)
                if (arow[r] >= s)
                    *(f32x4*)&a0[adst[r]] = (f32x4){0.f, 0.f, 0.f, 0.f};
            __syncthreads();
        }
        LOAD_A32(a0);
        LOAD_B4(cur);
        if (kt + 1 < NKT) STAGE_B(nxt, kt + 1);
        if (kt + 2 < NKT) STAGE_A(a2, kt + 2);   // a2 last read P(kt-1)
        __builtin_amdgcn_s_setprio(1);
        MFMA16();
        __builtin_amdgcn_s_setprio(0);

        // rotate A buffers
        float* ta = a0; a0 = a1; a1 = a2; a2 = ta;
    }

    // ---- epilogue: bias + store ----
    const int row0 = m0 + wm * 64 + (lane >> 4) * 4;
    const int col0 = n0 + wn * 64 + fr;
#pragma unroll
    for (int i = 0; i < 4; ++i)
#pragma unroll
        for (int q = 0; q < 4; ++q)
#pragma unroll
            for (int rr = 0; rr < 4; ++rr)
                out[(size_t)(row0 + i * 16 + rr) * D_OUT + (col0 + q * 16)] =
                    acc[i][q][rr] + bias_v[q];

#undef STAGE_A
#undef STAGE_B
#undef LOAD_A32
#undef LOAD_B4
#undef MFMA16
}

// ---------------------------------------------------------------------------
extern "C" void kernel_launch(void* const* d_in, const int* in_sizes, int n_in,
                              void* d_out, int out_size, void* d_ws, size_t ws_size,
                              hipStream_t stream) {
    const float* x    = (const float*)d_in[0];
    const int*   mask = (const int*)d_in[1];
    const float* W    = (const float*)d_in[2];
    const float* bias = (const float*)d_in[3];
    float*       out  = (float*)d_out;

    __bf16* wsW   = (__bf16*)((char*)d_ws + WS_W_OFF);
    int*    s_arr = (int*)((char*)d_ws + WS_S_OFF);

    prep_kernel<<<dim3(16 + D_OUT), dim3(256), 0, stream>>>(
        mask, W, s_arr, wsW);

    const int grid = (M_DIM / BM) * (D_OUT / BN);  // 128 * 8 = 1024
    gemm_kernel<<<dim3(grid), dim3(256), 0, stream>>>(
        x, wsW, bias, s_arr, out);
}